// Round 1
// 281.926 us; speedup vs baseline: 1.0246x; 1.0246x over previous
//
#include <hip/hip_runtime.h>

#define LEN 100
#define NR 400   // B*L

__device__ __forceinline__ float siluf_(float x) { return x / (1.0f + __expf(-x)); }
__device__ __forceinline__ float softplusf_(float x) {
    return (x > 20.f) ? x : log1pf(expf(x));
}

typedef float f4v __attribute__((ext_vector_type(4)));
__device__ __forceinline__ float4 nt_load4(const float* p) {
    f4v t = __builtin_nontemporal_load((const f4v*)p);
    return make_float4(t.x, t.y, t.z, t.w);
}
__device__ __forceinline__ void nt_store4(float* p, float4 v) {
    f4v t; t.x = v.x; t.y = v.y; t.z = v.z; t.w = v.w;
    __builtin_nontemporal_store(t, (f4v*)p);
}

// Fused front: in_proj (+recompute 4 rows for conv) + causal conv + silu
//            + x_proj(B half) + dt_proj + softplus + silu(z)
__global__ void __launch_bounds__(256) k_front(
    const float* __restrict__ hidden, const float* __restrict__ ipw, const float* __restrict__ ipb,
    const float* __restrict__ cw, const float* __restrict__ cb,
    const float* __restrict__ xpw, const float* __restrict__ dtw, const float* __restrict__ dtb,
    float* __restrict__ xact, float* __restrict__ Bm, float* __restrict__ dt,
    float* __restrict__ zs)
{
    int r = blockIdx.x;          // 0..399
    int l = r % LEN;
    int j = threadIdx.x;         // 0..255
    int lb = l < 3 ? l : 3;
    __shared__ float hid[4][128];
    __shared__ __align__(16) float xs[256];

    // stage hidden rows r-k (k=0..3); zero-fill rows before sequence start
    for (int e = j; e < 512; e += 256) {
        int k = e >> 7;
        int c = e & 127;
        hid[k][c] = (k <= lb) ? hidden[(size_t)(r - k) * 128 + c] : 0.f;
    }
    __syncthreads();

    // x_pre for rows r-k (k=0..3) and z for row r
    float b0 = ipb[j];
    float xp0 = b0, xp1 = b0, xp2 = b0, xp3 = b0;
    float z = ipb[256 + j];
    const float* wx = ipw + (size_t)j * 128;
    const float* wz = ipw + (size_t)(256 + j) * 128;
#pragma unroll 8
    for (int c = 0; c < 128; c += 4) {
        float4 w = *(const float4*)(wx + c);
        xp0 += w.x * hid[0][c] + w.y * hid[0][c+1] + w.z * hid[0][c+2] + w.w * hid[0][c+3];
        xp1 += w.x * hid[1][c] + w.y * hid[1][c+1] + w.z * hid[1][c+2] + w.w * hid[1][c+3];
        xp2 += w.x * hid[2][c] + w.y * hid[2][c+1] + w.z * hid[2][c+2] + w.w * hid[2][c+3];
        xp3 += w.x * hid[3][c] + w.y * hid[3][c+1] + w.z * hid[3][c+2] + w.w * hid[3][c+3];
        float4 v = *(const float4*)(wz + c);
        z += v.x * hid[0][c] + v.y * hid[0][c+1] + v.z * hid[0][c+2] + v.w * hid[0][c+3];
    }
    // causal conv: out[l] = sum_k cw[3-k] * x[l-k]
    float4 w4 = *(const float4*)(cw + j * 4);
    float conv = cb[j] + w4.w * xp0;
    if (lb >= 1) conv += w4.z * xp1;
    if (lb >= 2) conv += w4.y * xp2;
    if (lb >= 3) conv += w4.x * xp3;
    float xa = siluf_(conv);
    xs[j] = xa;
    xact[r * 256 + j] = xa;
    zs[r * 256 + j] = siluf_(z);
    __syncthreads();

    // Bm = xs . xpw[j], dt = softplus(xs . dtw[j] + dtb[j])
    float accB = 0.f, accD = dtb[j];
    const float* bw = xpw + (size_t)j * 256;
    const float* dw = dtw + (size_t)j * 256;
#pragma unroll 8
    for (int c = 0; c < 256; c += 4) {
        float4 bwv = *(const float4*)(bw + c);
        float4 dwv = *(const float4*)(dw + c);
        float4 xv  = *(const float4*)(xs + c);
        accB += bwv.x * xv.x + bwv.y * xv.y + bwv.z * xv.z + bwv.w * xv.w;
        accD += dwv.x * xv.x + dwv.y * xv.y + dwv.z * xv.z + dwv.w * xv.w;
    }
    Bm[r * 256 + j] = accB;
    dt[r * 256 + j] = softplusf_(accD);
}

// Main scan: block = (l, 16-wide d-slice); 4 waves, each wave owns 4 d-rows
// and processes ALL 4 batches for them. C[l,d,n] and A[d,n] are loaded ONCE
// per block and reused x4 in registers (C logical traffic 105MB -> 26MB),
// A = -exp(A_log) computed inline (kills the separate k_nega dispatch).
__global__ void __launch_bounds__(256, 4) k_scan(
    const float* __restrict__ state, const float* __restrict__ alog,
    const float* __restrict__ Cp, const float* __restrict__ dtg,
    const float* __restrict__ Bm, float* __restrict__ ostate, float* __restrict__ ypart)
{
    int bid = blockIdx.x;            // 1600 = 100 l * 16 slices
    int l = bid >> 4, sl = bid & 15;
    int tid = threadIdx.x;
    int wid = tid >> 6, lane = tid & 63, n0 = lane * 4;
    int d0 = sl * 16 + wid * 4;      // this wave's first d-row

    const float* cp = Cp + ((size_t)(l * 256 + d0)) * 256 + n0;
    const float* ap = alog + (size_t)d0 * 256 + n0;

    float4 Bv[4], dtq[4], acc[4];
    size_t soff[4];
#pragma unroll
    for (int b = 0; b < 4; ++b) {
        int r = b * LEN + l;
        Bv[b] = *(const float4*)(Bm + r * 256 + n0);
        dtq[b] = *(const float4*)(dtg + r * 256 + d0);   // dt for d0..d0+3
        soff[b] = ((size_t)(r * 256 + d0)) * 256 + n0;
        acc[b] = make_float4(0.f, 0.f, 0.f, 0.f);
    }

#pragma unroll
    for (int i = 0; i < 4; ++i) {
        float4 av = *(const float4*)(ap + (size_t)i * 256);
        float4 cv = *(const float4*)(cp + (size_t)i * 256);
        float4 na;
        na.x = -expf(av.x); na.y = -expf(av.y);
        na.z = -expf(av.z); na.w = -expf(av.w);
#pragma unroll
        for (int b = 0; b < 4; ++b) {
            float dtv = (i == 0) ? dtq[b].x : (i == 1) ? dtq[b].y
                      : (i == 2) ? dtq[b].z : dtq[b].w;          // folds: i is static
            float4 s = nt_load4(state + soff[b] + (size_t)i * 256);
            float4 as;
            as.x = s.x * __expf(dtv * na.x) + dtv * Bv[b].x;
            as.y = s.y * __expf(dtv * na.y) + dtv * Bv[b].y;
            as.z = s.z * __expf(dtv * na.z) + dtv * Bv[b].z;
            as.w = s.w * __expf(dtv * na.w) + dtv * Bv[b].w;
            nt_store4(ostate + soff[b] + (size_t)i * 256, as);
            acc[b].x += as.x * cv.x;
            acc[b].y += as.y * cv.y;
            acc[b].z += as.z * cv.z;
            acc[b].w += as.w * cv.w;
        }
    }

    // cross-wave reduce: wave w gathers batch b=w across the 4 waves' d-rows
    __shared__ __align__(16) float accs[4][4][256];   // [wid][batch][n]
#pragma unroll
    for (int b = 0; b < 4; ++b)
        *(float4*)(&accs[wid][b][n0]) = acc[b];
    __syncthreads();
    {
        float4 t0 = *(const float4*)(&accs[0][wid][n0]);
        float4 t1 = *(const float4*)(&accs[1][wid][n0]);
        float4 t2 = *(const float4*)(&accs[2][wid][n0]);
        float4 t3 = *(const float4*)(&accs[3][wid][n0]);
        float4 o;
        o.x = (t0.x + t1.x) + (t2.x + t3.x);
        o.y = (t0.y + t1.y) + (t2.y + t3.y);
        o.z = (t0.z + t1.z) + (t2.z + t3.z);
        o.w = (t0.w + t1.w) + (t2.w + t3.w);
        *(float4*)(ypart + ((size_t)(sl * NR + wid * LEN + l)) * 256 + n0) = o;
    }
}

// Fused back: y = (sum_sl ypart + D1*xact) * silu(z); out = y @ out_proj_w.T + b
__global__ void __launch_bounds__(256) k_back(
    const float* __restrict__ ypart, const float* __restrict__ xact,
    const float* __restrict__ zs, const float* __restrict__ D1,
    const float* __restrict__ ow, const float* __restrict__ ob,
    float* __restrict__ out)
{
    int r = blockIdx.x;        // 0..399
    int t = threadIdx.x;       // 0..255
    __shared__ __align__(16) float ys[256];
    const int S = NR * 256;
    int idx = r * 256 + t;
    float v = 0.f;
#pragma unroll
    for (int q = 0; q < 16; q++) v += ypart[q * S + idx];
    v += D1[t] * xact[idx];
    v *= zs[idx];
    ys[t] = v;
    __syncthreads();
    if (t < 128) {
        const float* wp = ow + (size_t)t * 256;
        float acc = ob[t];
#pragma unroll 8
        for (int c = 0; c < 256; c += 4) {
            float4 w = *(const float4*)(wp + c);
            float4 x = *(const float4*)(ys + c);
            acc += w.x * x.x + w.y * x.y + w.z * x.z + w.w * x.w;
        }
        out[r * 128 + t] = acc;
    }
}

extern "C" void kernel_launch(void* const* d_in, const int* in_sizes, int n_in,
                              void* d_out, int out_size, void* d_ws, size_t ws_size,
                              hipStream_t stream) {
    const float* hidden = (const float*)d_in[0];
    const float* state  = (const float*)d_in[1];
    const float* ipw    = (const float*)d_in[2];
    const float* ipb    = (const float*)d_in[3];
    const float* cw     = (const float*)d_in[4];
    const float* cb     = (const float*)d_in[5];
    const float* xpw    = (const float*)d_in[6];
    const float* dtw    = (const float*)d_in[7];
    const float* dtb    = (const float*)d_in[8];
    const float* alog   = (const float*)d_in[9];
    const float* D1     = (const float*)d_in[10];
    const float* Cp     = (const float*)d_in[11];
    const float* opw    = (const float*)d_in[12];
    const float* opb    = (const float*)d_in[13];

    float* out    = (float*)d_out;             // (4,100,128) = 51200
    float* ostate = out + 51200;               // (4,100,256,256)

    float* ws    = (float*)d_ws;
    float* xact  = ws;                 // 102400
    float* Bm    = ws + 102400;        // 102400
    float* dt    = ws + 204800;        // 102400
    float* zs    = ws + 307200;        // 102400
    float* ypart = ws + 409600;        // 16 * 400 * 256 = 1638400

    k_front<<<400,  256, 0, stream>>>(hidden, ipw, ipb, cw, cb, xpw, dtw, dtb,
                                      xact, Bm, dt, zs);
    k_scan <<<1600, 256, 0, stream>>>(state, alog, Cp, dt, Bm, ostate, ypart);
    k_back <<<400,  256, 0, stream>>>(ypart, xact, zs, D1, opw, opb, out);
}